// Round 3
// baseline (2805.398 us; speedup 1.0000x reference)
//
#include <hip/hip_runtime.h>

// InverseTransitionModel, B=32768, H=256, 10 GRU steps.
// v3: rollout block = 128 rows (halves weight re-fetch: 3GB demand vs 6GB),
// wave = 128 rows x 16 cols (rt=8, ct=1), 2 col-half passes; h0/h1 in LDS
// with XOR-swizzled 16B granules (kills the 8-way ds_read_b128 conflicts).
// bf16 MFMA 16x16x32, fp32 accum/elementwise.

#define HS 264   // k_encode LDS stride (unchanged, not the hot kernel)

typedef __attribute__((ext_vector_type(8))) short short8;
typedef __attribute__((ext_vector_type(4))) float fvec4;

__device__ __forceinline__ float bf2f(unsigned short u) {
    union { unsigned int u; float f; } x; x.u = ((unsigned int)u) << 16; return x.f;
}
__device__ __forceinline__ unsigned short f2bf(float f) {
    union { float f; unsigned int u; } x; x.f = f;
    unsigned int r = x.u + 0x7fffu + ((x.u >> 16) & 1u);   // RNE
    return (unsigned short)(r >> 16);
}
__device__ __forceinline__ float sigm(float x)   { return __builtin_amdgcn_rcpf(1.f + __expf(-x)); }
__device__ __forceinline__ float tanh_f(float x) { return 2.f * __builtin_amdgcn_rcpf(1.f + __expf(-2.f * x)) - 1.f; }

__device__ __forceinline__ short8 ld8(const unsigned short* p) {
    return *reinterpret_cast<const short8*>(p);
}
__device__ __forceinline__ fvec4 mfma16(short8 a, short8 b, fvec4 c) {
    return __builtin_amdgcn_mfma_f32_16x16x32_bf16(a, b, c, 0, 0, 0);
}

// swizzled LDS offset (shorts): row stride 256 shorts, 16B granule XOR row&7
__device__ __forceinline__ int swz(int row, int col) {
    return row * 256 + ((((col >> 3) ^ (row & 7)) & 31) * 8) + (col & 7);
}

// ---------------- weight cast fp32 -> bf16 ----------------
// ws short layout: W1[262144] W2[65536] Winit[131072] Wih0[6144]
//                  Whh0[196608] Wih1[196608] Whh1[196608] Wa[2048]
__global__ __launch_bounds__(256) void k_prep(
    const float* __restrict__ W1, const float* __restrict__ W2,
    const float* __restrict__ Winit, const float* __restrict__ Wih0,
    const float* __restrict__ Whh0, const float* __restrict__ Wih1,
    const float* __restrict__ Whh1, const float* __restrict__ Wa,
    unsigned short* __restrict__ wb)
{
    int i = blockIdx.x * 256 + threadIdx.x;
    if (i >= 1056768) return;
    float v;
    if      (i <  262144) v = W1[i];
    else if (i <  327680) v = W2[i - 262144];
    else if (i <  458752) v = Winit[i - 327680];
    else if (i <  464896) v = Wih0[i - 458752];
    else if (i <  661504) v = Whh0[i - 464896];
    else if (i <  858112) v = Wih1[i - 661504];
    else if (i < 1054720) v = Whh1[i - 858112];
    else                  v = Wa[i - 1054720];
    wb[i] = f2bf(v);
}

// ---------------- encoder: fc1 -> LN -> ReLU -> fc2 -> ReLU -> init -----------
// (unchanged from v2 — not the hot kernel)
__global__ __launch_bounds__(512, 2) void k_encode(
    const float* __restrict__ ini, const float* __restrict__ fin,
    const unsigned short* __restrict__ W1b, const float* __restrict__ b1,
    const float* __restrict__ lng, const float* __restrict__ lnb,
    const unsigned short* __restrict__ W2b, const float* __restrict__ b2,
    const unsigned short* __restrict__ Winitb, const float* __restrict__ binit,
    unsigned short* __restrict__ h0g, unsigned short* __restrict__ h1g)
{
    __shared__ unsigned short hb[64 * HS];
    __shared__ float ps[64][8][2];
    __shared__ float st[64][2];
    const int tid = threadIdx.x, lane = tid & 63, w = tid >> 6;
    const int l15 = lane & 15, q = lane >> 4;
    const int rows0 = blockIdx.x * 64;
    const int c0 = w * 32;
    const fvec4 fz = {0.f, 0.f, 0.f, 0.f};

    fvec4 acc[4][2];
#pragma unroll
    for (int rt = 0; rt < 4; ++rt) { acc[rt][0] = fz; acc[rt][1] = fz; }
    for (int kc = 0; kc < 32; ++kc) {
        const int k0 = kc * 32 + q * 8;
        short8 a8[4];
#pragma unroll
        for (int rt = 0; rt < 4; ++rt) {
            const int grow = rows0 + rt * 16 + l15;
            const float* src = (k0 < 512) ? (ini + grow * 512 + k0)
                                          : (fin + grow * 512 + (k0 - 512));
            fvec4 v0 = *reinterpret_cast<const fvec4*>(src);
            fvec4 v1 = *reinterpret_cast<const fvec4*>(src + 4);
            short8 t;
            t[0]=(short)f2bf(v0[0]); t[1]=(short)f2bf(v0[1]); t[2]=(short)f2bf(v0[2]); t[3]=(short)f2bf(v0[3]);
            t[4]=(short)f2bf(v1[0]); t[5]=(short)f2bf(v1[1]); t[6]=(short)f2bf(v1[2]); t[7]=(short)f2bf(v1[3]);
            a8[rt] = t;
        }
#pragma unroll
        for (int ct = 0; ct < 2; ++ct) {
            short8 b8 = ld8(W1b + (c0 + ct * 16 + l15) * 1024 + k0);
#pragma unroll
            for (int rt = 0; rt < 4; ++rt) acc[rt][ct] = mfma16(a8[rt], b8, acc[rt][ct]);
        }
    }
    float bv[2] = { b1[c0 + l15], b1[c0 + 16 + l15] };
#pragma unroll
    for (int rt = 0; rt < 4; ++rt)
#pragma unroll
        for (int r = 0; r < 4; ++r) {
            float s = 0.f, s2 = 0.f;
#pragma unroll
            for (int ct = 0; ct < 2; ++ct) {
                float v = acc[rt][ct][r] + bv[ct];
                acc[rt][ct][r] = v;
                s += v; s2 += v * v;
            }
#pragma unroll
            for (int off = 1; off < 16; off <<= 1) {
                s  += __shfl_xor(s,  off, 64);
                s2 += __shfl_xor(s2, off, 64);
            }
            if (l15 == 0) {
                int row = rt * 16 + q * 4 + r;
                ps[row][w][0] = s; ps[row][w][1] = s2;
            }
        }
    __syncthreads();
    if (tid < 64) {
        float s = 0.f, s2 = 0.f;
#pragma unroll
        for (int j = 0; j < 8; ++j) { s += ps[tid][j][0]; s2 += ps[tid][j][1]; }
        float mu = s * (1.f / 256.f);
        float var = s2 * (1.f / 256.f) - mu * mu;
        st[tid][0] = mu; st[tid][1] = rsqrtf(var + 1e-5f);
    }
    __syncthreads();
    {
        float gv[2]  = { lng[c0 + l15], lng[c0 + 16 + l15] };
        float bbv[2] = { lnb[c0 + l15], lnb[c0 + 16 + l15] };
#pragma unroll
        for (int rt = 0; rt < 4; ++rt)
#pragma unroll
            for (int ct = 0; ct < 2; ++ct)
#pragma unroll
                for (int r = 0; r < 4; ++r) {
                    int row = rt * 16 + q * 4 + r;
                    float v = (acc[rt][ct][r] - st[row][0]) * st[row][1] * gv[ct] + bbv[ct];
                    v = fmaxf(v, 0.f);
                    hb[row * HS + c0 + ct * 16 + l15] = f2bf(v);
                }
    }
    __syncthreads();
    fvec4 acc2[4][2];
#pragma unroll
    for (int rt = 0; rt < 4; ++rt) { acc2[rt][0] = fz; acc2[rt][1] = fz; }
    for (int kc = 0; kc < 8; ++kc) {
        const int k0 = kc * 32 + q * 8;
        short8 a8[4];
#pragma unroll
        for (int rt = 0; rt < 4; ++rt) a8[rt] = ld8(hb + (rt * 16 + l15) * HS + k0);
#pragma unroll
        for (int ct = 0; ct < 2; ++ct) {
            short8 b8 = ld8(W2b + (c0 + ct * 16 + l15) * 256 + k0);
#pragma unroll
            for (int rt = 0; rt < 4; ++rt) acc2[rt][ct] = mfma16(a8[rt], b8, acc2[rt][ct]);
        }
    }
    {
        float b2v[2] = { b2[c0 + l15], b2[c0 + 16 + l15] };
        unsigned short stg[4][2][4];
#pragma unroll
        for (int rt = 0; rt < 4; ++rt)
#pragma unroll
            for (int ct = 0; ct < 2; ++ct)
#pragma unroll
                for (int r = 0; r < 4; ++r)
                    stg[rt][ct][r] = f2bf(fmaxf(acc2[rt][ct][r] + b2v[ct], 0.f));
        __syncthreads();
#pragma unroll
        for (int rt = 0; rt < 4; ++rt)
#pragma unroll
            for (int ct = 0; ct < 2; ++ct)
#pragma unroll
                for (int r = 0; r < 4; ++r)
                    hb[(rt * 16 + q * 4 + r) * HS + c0 + ct * 16 + l15] = stg[rt][ct][r];
    }
    __syncthreads();
    const int c0i = w * 64;
    fvec4 a3[4][4];
#pragma unroll
    for (int rt = 0; rt < 4; ++rt)
#pragma unroll
        for (int ct = 0; ct < 4; ++ct) a3[rt][ct] = fz;
    for (int kc = 0; kc < 8; ++kc) {
        const int k0 = kc * 32 + q * 8;
        short8 a8[4];
#pragma unroll
        for (int rt = 0; rt < 4; ++rt) a8[rt] = ld8(hb + (rt * 16 + l15) * HS + k0);
#pragma unroll
        for (int ct = 0; ct < 4; ++ct) {
            short8 b8 = ld8(Winitb + (c0i + ct * 16 + l15) * 256 + k0);
#pragma unroll
            for (int rt = 0; rt < 4; ++rt) a3[rt][ct] = mfma16(a8[rt], b8, a3[rt][ct]);
        }
    }
#pragma unroll
    for (int ct = 0; ct < 4; ++ct) {
        const int j = c0i + ct * 16 + l15;
        const float bz = binit[j];
        const int half = j >> 8, cc = j & 255;
#pragma unroll
        for (int rt = 0; rt < 4; ++rt)
#pragma unroll
            for (int r = 0; r < 4; ++r) {
                const int i = rows0 + rt * 16 + q * 4 + r;
                const unsigned short v = f2bf(a3[rt][ct][r] + bz);
                if (i < 16384) h0g[(2 * i + half) * 256 + cc] = v;
                else           h1g[(2 * (i - 16384) + half) * 256 + cc] = v;
            }
    }
}

// ---------------- fused 10-step rollout (v3) -------------------------------
// block = 128 rows, 8 waves; wave = 128 rows x 16 cols (rt=8, ct=1);
// 2 col-half passes cover 256 cols. h0/h1 swizzled in LDS.
__global__ __launch_bounds__(512, 2) void k_roll(
    const unsigned short* __restrict__ h0g, const unsigned short* __restrict__ h1g,
    const unsigned short* __restrict__ Wih0b, const unsigned short* __restrict__ Whh0b,
    const unsigned short* __restrict__ Wih1b, const unsigned short* __restrict__ Whh1b,
    const unsigned short* __restrict__ Wab,
    const float* __restrict__ bih0, const float* __restrict__ bhh0,
    const float* __restrict__ bih1, const float* __restrict__ bhh1,
    const float* __restrict__ ba, float* __restrict__ out)
{
    __shared__ unsigned short h0s[128 * 256];
    __shared__ unsigned short h1s[128 * 256];
    __shared__ unsigned short avs[128 * 8];
    const int tid = threadIdx.x, lane = tid & 63, w = tid >> 6;
    const int l15 = lane & 15, q = lane >> 4;
    const int rows0 = blockIdx.x * 128;
    const fvec4 fz = {0.f, 0.f, 0.f, 0.f};
    const short8 z8 = {0,0,0,0,0,0,0,0};

    // ---- load h state global -> LDS (swizzled) ----
    for (int it = tid; it < 128 * 32; it += 512) {
        const int row = it >> 5, g = it & 31;
        const int dst = row * 256 + (((g ^ (row & 7)) & 31) << 3);
        *reinterpret_cast<short8*>(h0s + dst) = ld8(h0g + (rows0 + row) * 256 + g * 8);
        *reinterpret_cast<short8*>(h1s + dst) = ld8(h1g + (rows0 + row) * 256 + g * 8);
    }
    // ---- per-lane bias constants for both col-halves ----
    float br0[2], bz0[2], bi0[2], bh0[2], br1[2], bz1[2], bi1[2], bh1[2];
#pragma unroll
    for (int h = 0; h < 2; ++h) {
        const int c = h * 128 + w * 16 + l15;
        br0[h] = bih0[c] + bhh0[c];
        bz0[h] = bih0[256 + c] + bhh0[256 + c];
        bi0[h] = bih0[512 + c];
        bh0[h] = bhh0[512 + c];
        br1[h] = bih1[c] + bhh1[c];
        bz1[h] = bih1[256 + c] + bhh1[256 + c];
        bi1[h] = bih1[512 + c];
        bh1[h] = bhh1[512 + c];
    }
    const float bav = ba[l15 & 7];
    __syncthreads();

    for (int t = 0; t < 10; ++t) {
        // ================= GRU cell 0 =================
        unsigned int stg[2][16];   // staged hn (bf16 pairs) for both halves
#pragma unroll
        for (int half = 0; half < 2; ++half) {
            const int cw = half * 128 + w * 16 + l15;   // this lane's output col
            fvec4 aR[8], aZ[8], aNi[8], aNh[8];
#pragma unroll
            for (int rt = 0; rt < 8; ++rt) { aR[rt]=fz; aZ[rt]=fz; aNi[rt]=fz; aNh[rt]=fz; }
            for (int kc = 0; kc < 8; ++kc) {
                const int k0 = kc * 32 + q * 8;
                short8 ah[8];
#pragma unroll
                for (int rt = 0; rt < 8; ++rt) ah[rt] = ld8(h0s + swz(rt * 16 + l15, k0));
                const unsigned short* wp = Whh0b + cw * 256 + k0;
                short8 wr = ld8(wp);
                short8 wz = ld8(wp + 65536);
                short8 wn = ld8(wp + 131072);
#pragma unroll
                for (int rt = 0; rt < 8; ++rt) {
                    aR[rt]  = mfma16(ah[rt], wr, aR[rt]);
                    aZ[rt]  = mfma16(ah[rt], wz, aZ[rt]);
                    aNh[rt] = mfma16(ah[rt], wn, aNh[rt]);
                }
            }
            if (t > 0) {           // action GEMM K=8 in one K=32 chunk
                short8 av[8];
#pragma unroll
                for (int rt = 0; rt < 8; ++rt) {
                    short8 v = ld8(avs + (rt * 16 + l15) * 8);
                    av[rt] = (q == 0) ? v : z8;
                }
                const unsigned short* wp = Wih0b + cw * 8;
                short8 wr = ld8(wp);
                short8 wz = ld8(wp + 2048);
                short8 wn = ld8(wp + 4096);
#pragma unroll
                for (int rt = 0; rt < 8; ++rt) {
                    aR[rt]  = mfma16(av[rt], wr, aR[rt]);
                    aZ[rt]  = mfma16(av[rt], wz, aZ[rt]);
                    aNi[rt] = mfma16(av[rt], wn, aNi[rt]);
                }
            }
#pragma unroll
            for (int rt = 0; rt < 8; ++rt) {
                unsigned int p0 = 0, p1 = 0;
#pragma unroll
                for (int r = 0; r < 4; ++r) {
                    const int row = rt * 16 + q * 4 + r;
                    const float hold = bf2f(h0s[swz(row, cw)]);
                    const float rr = sigm(aR[rt][r] + br0[half]);
                    const float zz = sigm(aZ[rt][r] + bz0[half]);
                    const float nn = tanh_f(aNi[rt][r] + bi0[half] + rr * (aNh[rt][r] + bh0[half]));
                    const unsigned int v = f2bf((1.f - zz) * nn + zz * hold);
                    if (r < 2) p0 |= v << (16 * r); else p1 |= v << (16 * (r - 2));
                }
                stg[half][rt * 2]     = p0;
                stg[half][rt * 2 + 1] = p1;
            }
        }
        __syncthreads();   // all reads of h0s done
#pragma unroll
        for (int half = 0; half < 2; ++half) {
            const int cw = half * 128 + w * 16 + l15;
#pragma unroll
            for (int rt = 0; rt < 8; ++rt)
#pragma unroll
                for (int r = 0; r < 4; ++r) {
                    const unsigned int pk = stg[half][rt * 2 + (r >> 1)];
                    h0s[swz(rt * 16 + q * 4 + r, cw)] =
                        (unsigned short)(pk >> (16 * (r & 1)));
                }
        }
        __syncthreads();   // h0s = h0n
        // ================= GRU cell 1 =================
#pragma unroll
        for (int half = 0; half < 2; ++half) {
            const int cw = half * 128 + w * 16 + l15;
            fvec4 aR[8], aZ[8], aNi[8], aNh[8];
#pragma unroll
            for (int rt = 0; rt < 8; ++rt) { aR[rt]=fz; aZ[rt]=fz; aNi[rt]=fz; aNh[rt]=fz; }
            for (int kc = 0; kc < 8; ++kc) {
                const int k0 = kc * 32 + q * 8;
                {
                    short8 ai[8];
#pragma unroll
                    for (int rt = 0; rt < 8; ++rt) ai[rt] = ld8(h0s + swz(rt * 16 + l15, k0));
                    const unsigned short* wi = Wih1b + cw * 256 + k0;
                    short8 wir = ld8(wi);
                    short8 wiz = ld8(wi + 65536);
                    short8 win = ld8(wi + 131072);
#pragma unroll
                    for (int rt = 0; rt < 8; ++rt) {
                        aR[rt]  = mfma16(ai[rt], wir, aR[rt]);
                        aZ[rt]  = mfma16(ai[rt], wiz, aZ[rt]);
                        aNi[rt] = mfma16(ai[rt], win, aNi[rt]);
                    }
                }
                {
                    short8 ah[8];
#pragma unroll
                    for (int rt = 0; rt < 8; ++rt) ah[rt] = ld8(h1s + swz(rt * 16 + l15, k0));
                    const unsigned short* wh = Whh1b + cw * 256 + k0;
                    short8 whr = ld8(wh);
                    short8 whz = ld8(wh + 65536);
                    short8 whn = ld8(wh + 131072);
#pragma unroll
                    for (int rt = 0; rt < 8; ++rt) {
                        aR[rt]  = mfma16(ah[rt], whr, aR[rt]);
                        aZ[rt]  = mfma16(ah[rt], whz, aZ[rt]);
                        aNh[rt] = mfma16(ah[rt], whn, aNh[rt]);
                    }
                }
            }
#pragma unroll
            for (int rt = 0; rt < 8; ++rt) {
                unsigned int p0 = 0, p1 = 0;
#pragma unroll
                for (int r = 0; r < 4; ++r) {
                    const int row = rt * 16 + q * 4 + r;
                    const float hold = bf2f(h1s[swz(row, cw)]);
                    const float rr = sigm(aR[rt][r] + br1[half]);
                    const float zz = sigm(aZ[rt][r] + bz1[half]);
                    const float nn = tanh_f(aNi[rt][r] + bi1[half] + rr * (aNh[rt][r] + bh1[half]));
                    const unsigned int v = f2bf((1.f - zz) * nn + zz * hold);
                    if (r < 2) p0 |= v << (16 * r); else p1 |= v << (16 * (r - 2));
                }
                stg[half][rt * 2]     = p0;
                stg[half][rt * 2 + 1] = p1;
            }
        }
        __syncthreads();   // all reads of h1s done
#pragma unroll
        for (int half = 0; half < 2; ++half) {
            const int cw = half * 128 + w * 16 + l15;
#pragma unroll
            for (int rt = 0; rt < 8; ++rt)
#pragma unroll
                for (int r = 0; r < 4; ++r) {
                    const unsigned int pk = stg[half][rt * 2 + (r >> 1)];
                    h1s[swz(rt * 16 + q * 4 + r, cw)] =
                        (unsigned short)(pk >> (16 * (r & 1)));
                }
        }
        __syncthreads();   // h1s = h1n
        // ================= logits + softmax -> a (each wave: 16 rows) ========
        {
            fvec4 f = fz;
            for (int kc = 0; kc < 8; ++kc) {
                const int k0 = kc * 32 + q * 8;
                short8 a8 = ld8(h1s + swz(w * 16 + l15, k0));
                short8 b8 = ld8(Wab + (l15 & 7) * 256 + k0);   // cols 8-15 dup
                f = mfma16(a8, b8, f);
            }
#pragma unroll
            for (int r = 0; r < 4; ++r) {
                float s = f[r] + bav;
                float m = s;
                m = fmaxf(m, __shfl_xor(m, 1, 64));
                m = fmaxf(m, __shfl_xor(m, 2, 64));
                m = fmaxf(m, __shfl_xor(m, 4, 64));
                float e = __expf(s - m);
                float se = e;
                se += __shfl_xor(se, 1, 64);
                se += __shfl_xor(se, 2, 64);
                se += __shfl_xor(se, 4, 64);
                if (l15 < 8) {
                    const int lrow = w * 16 + q * 4 + r;
                    out[(rows0 + lrow) * 80 + t * 8 + l15] = s;
                    avs[lrow * 8 + l15] = f2bf(e * __builtin_amdgcn_rcpf(se));
                }
            }
        }
        __syncthreads();   // a ready for next step
    }
}

// ---------------- host side -----------------------------------------------
extern "C" void kernel_launch(void* const* d_in, const int* in_sizes, int n_in,
                              void* d_out, int out_size, void* d_ws, size_t ws_size,
                              hipStream_t stream)
{
    const float* ini   = (const float*)d_in[0];
    const float* fin   = (const float*)d_in[1];
    /* d_in[2] = horizon (always 10) */
    const float* W1    = (const float*)d_in[3];
    const float* b1    = (const float*)d_in[4];
    const float* lng   = (const float*)d_in[5];
    const float* lnb   = (const float*)d_in[6];
    const float* W2    = (const float*)d_in[7];
    const float* b2    = (const float*)d_in[8];
    const float* Wih0  = (const float*)d_in[9];
    const float* Whh0  = (const float*)d_in[10];
    const float* bih0  = (const float*)d_in[11];
    const float* bhh0  = (const float*)d_in[12];
    const float* Wih1  = (const float*)d_in[13];
    const float* Whh1  = (const float*)d_in[14];
    const float* bih1  = (const float*)d_in[15];
    const float* bhh1  = (const float*)d_in[16];
    const float* Wa    = (const float*)d_in[17];
    const float* ba    = (const float*)d_in[18];
    const float* Winit = (const float*)d_in[19];
    const float* binit = (const float*)d_in[20];
    float* out = (float*)d_out;

    char* ws = (char*)d_ws;
    unsigned short* wb     = (unsigned short*)ws;
    unsigned short* W1b    = wb;
    unsigned short* W2b    = wb + 262144;
    unsigned short* Winitb = wb + 327680;
    unsigned short* Wih0b  = wb + 458752;
    unsigned short* Whh0b  = wb + 464896;
    unsigned short* Wih1b  = wb + 661504;
    unsigned short* Whh1b  = wb + 858112;
    unsigned short* Wab    = wb + 1054720;
    unsigned short* h0g = (unsigned short*)(ws + 2113536);
    unsigned short* h1g = (unsigned short*)(ws + 18890752);

    k_prep<<<dim3(4128), dim3(256), 0, stream>>>(W1, W2, Winit, Wih0, Whh0, Wih1, Whh1, Wa, wb);
    k_encode<<<dim3(512), dim3(512), 0, stream>>>(ini, fin, W1b, b1, lng, lnb, W2b, b2,
                                                  Winitb, binit, h0g, h1g);
    k_roll<<<dim3(256), dim3(512), 0, stream>>>(h0g, h1g, Wih0b, Whh0b, Wih1b, Whh1b, Wab,
                                                bih0, bhh0, bih1, bhh1, ba, out);
}